// Round 12
// baseline (102.581 us; speedup 1.0000x reference)
//
#include <hip/hip_runtime.h>
#include <math.h>

#define BB   256
#define SS   512
#define VV   150
#define NPOS (BB * SS)      // 131072
#define GRID 2048
#define EPSF 1e-8f

// ws layout:
// [0,32768)         float4 pA[2048]   {gathered_sum, mask_cnt, eos_logp_sum, eos_cnt}
// [32768,40960)     float  pB[2048]   attention partials
// [40960,44032)     int    pC[768]    rep counts per (row,n)
// [44032,45056)     int    hasx[256]  (has_t && !has_p) per row
// [45056,45060)     int    counter    (ticket for last-block reduce)
// [45312,176384)    uchar  toks[131072] argmax tokens

// order-preserving float->uint, top 24 bits; low 8 bits = 255-idx
// (first-occurrence argmax tie-break; collisions only when floats agree in
// top-24 mono bits -> negligible for pattern penalty; m recovered within
// 256 ULP for the rare eos softmax, error << threshold)
__device__ __forceinline__ unsigned key32(float f, int idx) {
    const unsigned u = __float_as_uint(f);
    const unsigned mono = ((int)u >= 0) ? (u | 0x80000000u) : ~u;
    return (mono & 0xFFFFFF00u) | (unsigned)(255 - idx);
}

__global__ __launch_bounds__(256) void kern_ab(
    const float* __restrict__ pred, const int* __restrict__ tgt,
    const float* __restrict__ attw, float4* __restrict__ pA,
    float* __restrict__ pB, unsigned char* __restrict__ toks,
    int* __restrict__ counter)
{
    __shared__ __align__(16) float slab[16 * VV];   // 9.6 KB
    __shared__ float shp[16];
    __shared__ float shb[4];
    const int tid  = threadIdx.x;
    const int lane = tid & 63;
    const int wid  = tid >> 6;

    if (blockIdx.x == 0 && tid == 0) *counter = 0;   // re-arm ticket each call

    // ======== phase A: 64 consecutive rows, 4 LDS stages of 16 rows ========
    // 16 threads per row; thread s scans cols [s*10, s*10+10) from LDS.
    const int s  = tid & 15;
    const int c0 = s * 10;                 // s==15 owns nothing (15*10 == 150)
    const int p  = tid >> 4;               // row within stage (0..15)
    float s_g = 0.f, s_mc = 0.f, s_el = 0.f, s_ec = 0.f;

    for (int it = 0; it < 4; ++it) {
        const int rbase = blockIdx.x * 64 + it * 16;
        const float4* g4 = (const float4*)(pred + (size_t)rbase * VV);
        float4* l4 = (float4*)slab;
        if (it) __syncthreads();           // previous scan done before overwrite
        #pragma unroll
        for (int k = 0; k < 3; ++k) {
            const int i = tid + k * 256;
            if (i < 600) l4[i] = g4[i];    // 16 rows = 600 float4, coalesced
        }
        __syncthreads();

        const float* row = slab + p * VV;
        unsigned key = 0;                  // below any real key
        if (s < 15) {
            const float2* r2 = (const float2*)(row + c0);
            #pragma unroll
            for (int j = 0; j < 5; ++j) {
                const float2 v = r2[j];
                key = max(key, key32(v.x, c0 + 2 * j));
                key = max(key, key32(v.y, c0 + 2 * j + 1));
            }
        }
        #pragma unroll
        for (int off = 1; off <= 8; off <<= 1)
            key = max(key, __shfl_xor(key, off));
        const int li = 255 - (int)(key & 0xFFu);

        const int t = tgt[rbase + p];      // uniform within 16-lane group
        if (t != 0) {
            if (s == 0)      s_mc += 1.f;
            if (s == t / 10) s_g += row[t];     // direct LDS gather, no shuffle
        }
        if (t == 2) {                      // rare, group-uniform
            const unsigned mono_hi = key & 0xFFFFFF00u;
            const float m = (mono_hi & 0x80000000u)
                          ? __uint_as_float(mono_hi & 0x7FFFFFFFu)
                          : __uint_as_float(~mono_hi);
            float ex = 0.f;
            if (s < 15) {
                #pragma unroll
                for (int j = 0; j < 10; ++j) ex += __expf(row[c0 + j] - m);
            }
            #pragma unroll
            for (int off = 1; off <= 8; off <<= 1) ex += __shfl_xor(ex, off);
            if (s == 0) {
                s_el += __logf(__expf(row[2] - m) / ex + EPSF);
                s_ec += 1.f;
            }
        }
        if (s == 0) toks[rbase + p] = (unsigned char)li;
    }

    // wave-reduce the four A accumulators
    #pragma unroll
    for (int off = 32; off > 0; off >>= 1) {
        s_g  += __shfl_xor(s_g,  off);
        s_mc += __shfl_xor(s_mc, off);
        s_el += __shfl_xor(s_el, off);
        s_ec += __shfl_xor(s_ec, off);
    }
    if (lane == 0) {
        shp[wid * 4 + 0] = s_g;  shp[wid * 4 + 1] = s_mc;
        shp[wid * 4 + 2] = s_el; shp[wid * 4 + 3] = s_ec;
    }

    // ======== phase B: attention entropy, contiguous chunk (R5 verbatim) ====
    {
        const float4* a4 = (const float4*)attw;
        const size_t bbase = (size_t)blockIdx.x * 8192;   // 131 KB/block
        float sb = 0.f;
        #pragma unroll 4
        for (int it = 0; it < 32; ++it) {
            const float4 v = a4[bbase + it * 256 + tid];
            sb += v.x * __logf(v.x + EPSF) + v.y * __logf(v.y + EPSF)
                + v.z * __logf(v.z + EPSF) + v.w * __logf(v.w + EPSF);
        }
        #pragma unroll
        for (int off = 32; off > 0; off >>= 1) sb += __shfl_xor(sb, off);
        if (lane == 0) shb[wid] = sb;
    }

    __syncthreads();
    if (tid == 0) {
        float4 r;
        r.x = shp[0] + shp[4] + shp[8]  + shp[12];
        r.y = shp[1] + shp[5] + shp[9]  + shp[13];
        r.z = shp[2] + shp[6] + shp[10] + shp[14];
        r.w = shp[3] + shp[7] + shp[11] + shp[15];
        pA[blockIdx.x] = r;
        pB[blockIdx.x] = shb[0] + shb[1] + shb[2] + shb[3];
    }
}

// ---- n-gram penalty (768 blocks) + last-block final reduce ----
__global__ __launch_bounds__(256) void kern_cf(
    const unsigned char* __restrict__ toks, const int* __restrict__ tgt,
    int* __restrict__ pC, int* __restrict__ hasx, int* __restrict__ counter,
    const float4* __restrict__ pA, const float* __restrict__ pB,
    float* __restrict__ out)
{
    const int blk = blockIdx.x;
    const int b = blk & 255;
    const int n = 2 + (blk >> 8);
    const int L = SS - n + 1;
    const int tid = threadIdx.x;

    __shared__ int tok[SS];
    __shared__ __align__(16) int h[SS];
    __shared__ int sflags;
    __shared__ int sticket;

    if (tid == 0) sflags = 0;
    const unsigned char* rt = toks + b * SS;
    tok[tid]       = rt[tid];
    tok[tid + 256] = rt[tid + 256];
    __syncthreads();

    if (blk < 256) {
        const int* trow = tgt + b * SS;
        int f = 0;
        if (trow[tid] == 2 || trow[tid + 256] == 2) f |= 1;
        if (tok[tid] == 2 || tok[tid + 256] == 2)   f |= 2;
        if (f) atomicOr(&sflags, f);
    }

    #pragma unroll
    for (int q = 0; q < 2; ++q) {
        const int i = tid + q * 256;
        int hv;
        if (i < L) {
            hv = tok[i];
            int mul = VV;
            for (int j = 1; j < n; ++j) { hv += tok[i + j] * mul; mul *= VV; }
        } else {
            hv = 0x7F000000 + i;   // unique sentinel, > any real hash (~5.06e8)
        }
        h[i] = hv;
    }
    __syncthreads();

    // count earlier duplicates; only scan j < i (bound rounded up to int4)
    const int i1 = tid, i2 = tid + 256;
    const int h1 = h[i1], h2 = h[i2];
    const int bound1 = (i1 & ~3) + 4;
    const int bound2 = (i2 & ~3) + 4;
    int c1 = 0, c2 = 0;
    for (int j = 0; j < bound1; j += 4) {
        const int4 hv = *(const int4*)&h[j];
        c1 += (hv.x == h1 && j     < i1) + (hv.y == h1 && j + 1 < i1)
            + (hv.z == h1 && j + 2 < i1) + (hv.w == h1 && j + 3 < i1);
    }
    for (int j = 0; j < bound2; j += 4) {
        const int4 hv = *(const int4*)&h[j];
        c2 += (hv.x == h2 && j     < i2) + (hv.y == h2 && j + 1 < i2)
            + (hv.z == h2 && j + 2 < i2) + (hv.w == h2 && j + 3 < i2);
    }
    int rep = (c1 >= 2) + (c2 >= 2);
    #pragma unroll
    for (int off = 32; off > 0; off >>= 1) rep += __shfl_xor(rep, off);
    __shared__ int w4[4];
    if ((tid & 63) == 0) w4[tid >> 6] = rep;
    __syncthreads();
    if (tid == 0) {
        pC[blk] = w4[0] + w4[1] + w4[2] + w4[3];
        if (blk < 256) hasx[b] = ((sflags & 1) && !(sflags & 2)) ? 1 : 0;
        __threadfence();                      // publish before ticket
        sticket = atomicAdd(counter, 1);
    }
    __syncthreads();
    if (sticket != 768 - 1) return;

    // ---- last block: final reduce (deterministic: fixed-order sums) ----
    __threadfence();                          // acquire others' pC/hasx
    const int lane = tid & 63;
    const int wid  = tid >> 6;
    double v[9];
    #pragma unroll
    for (int k = 0; k < 9; ++k) v[k] = 0.0;
    for (int i = tid; i < GRID; i += 256) {
        const float4 p = pA[i];
        v[0] += p.x; v[1] += p.y; v[2] += p.z; v[3] += p.w;
    }
    for (int i = tid; i < GRID; i += 256) v[4] += pB[i];
    v[5] = pC[tid]; v[6] = pC[tid + 256]; v[7] = pC[tid + 512];
    v[8] = (double)hasx[tid];

    #pragma unroll
    for (int off = 32; off > 0; off >>= 1)
        #pragma unroll
        for (int k = 0; k < 9; ++k) v[k] += __shfl_xor(v[k], off);

    __shared__ double sd[4][9];
    if (lane == 0)
        for (int k = 0; k < 9; ++k) sd[wid][k] = v[k];
    __syncthreads();

    if (tid == 0) {
        double r[9];
        for (int k = 0; k < 9; ++k) r[k] = sd[0][k] + sd[1][k] + sd[2][k] + sd[3][k];
        const double mainv    = -r[0] / fmax(r[1], 1.0);
        const double eos_loss = (r[3] > 0.0) ? (-r[2] / (double)NPOS) : 0.0;
        const double no_eos   = r[8] / (double)BB;
        const double eos_tot  = eos_loss + 0.5 * no_eos;
        const double att      = 0.1 * r[4] / (double)NPOS;  // = -mean(ent)*0.1
        const double pattern  = (0.2 * r[5] + 0.3 * r[6] + 0.4 * r[7]) / (double)BB;
        const double total    = mainv + 0.1 * pattern + 0.2 * eos_tot + 0.05 * att;
        out[0] = (float)total;   out[1] = (float)mainv; out[2] = (float)pattern;
        out[3] = (float)eos_tot; out[4] = (float)att;
    }
}

extern "C" void kernel_launch(void* const* d_in, const int* in_sizes, int n_in,
                              void* d_out, int out_size, void* d_ws, size_t ws_size,
                              hipStream_t stream)
{
    const float* pred = (const float*)d_in[0];
    const int*   tgt  = (const int*)d_in[1];
    const float* attw = (const float*)d_in[2];
    float* out = (float*)d_out;
    char*  ws  = (char*)d_ws;

    float4* pA   = (float4*)ws;
    float*  pB   = (float*)(ws + 32768);
    int*    pC   = (int*)(ws + 40960);
    int*    hasx = (int*)(ws + 44032);
    int*    cnt  = (int*)(ws + 45056);
    unsigned char* toks = (unsigned char*)(ws + 45312);

    kern_ab<<<GRID, 256, 0, stream>>>(pred, tgt, attw, pA, pB, toks, cnt);
    kern_cf<<<768, 256, 0, stream>>>(toks, tgt, pC, hasx, cnt, pA, pB, out);
}